// Round 3
// baseline (118.441 us; speedup 1.0000x reference)
//
#include <hip/hip_runtime.h>

#define N 4096
#define BLK 256
#define NEGF (-3.4e38f)

// 4B-aligned float4 (multi-dword global loads need only dword alignment on CDNA).
typedef float f4u __attribute__((ext_vector_type(4), aligned(4)));
typedef float f4a __attribute__((ext_vector_type(4), aligned(16)));

// Wave-level scan of one tril row: two running maxes (mask is exactly {0,1}):
//   bc = max score over mask==1, sm = max ana score over mask==0 (j<row).
// 4 independent accumulator pairs + branchless selects for ILP.
__device__ __forceinline__ void scan_row_wave(
    const float* __restrict__ ana_scores,
    const float* __restrict__ mask,
    const int row, const int lane,
    float& bc_out, float& sm_out)
{
    const long long base = (long long)row * (row - 1) / 2;
    const float* __restrict__ arow = ana_scores + base;
    const float* __restrict__ mrow = mask + (size_t)row * (size_t)N;

    float bc0 = NEGF, bc1 = NEGF, bc2 = NEGF, bc3 = NEGF;
    float sm0 = NEGF, sm1 = NEGF, sm2 = NEGF, sm3 = NEGF;

    // Peel so ana_scores + base + p is 16B-aligned.
    int p = (int)((4 - (base & 3)) & 3);
    if (p > row) p = row;
    const int nvec = (row - p) >> 2;      // float4 groups in [p, p+4*nvec)
    const int t0   = p + (nvec << 2);     // tail start

#pragma unroll 4
    for (int g = lane; g < nvec; g += 64) {
        const int j = p + (g << 2);
        const f4a s4 = *(const f4a*)(arow + j);   // 16B aligned
        const f4u m4 = *(const f4u*)(mrow + j);   // 4B aligned
        const bool o0 = (m4[0] != 0.0f);
        const bool o1 = (m4[1] != 0.0f);
        const bool o2 = (m4[2] != 0.0f);
        const bool o3 = (m4[3] != 0.0f);
        bc0 = fmaxf(bc0, o0 ? s4[0] : NEGF);
        sm0 = fmaxf(sm0, o0 ? NEGF : s4[0]);
        bc1 = fmaxf(bc1, o1 ? s4[1] : NEGF);
        sm1 = fmaxf(sm1, o1 ? NEGF : s4[1]);
        bc2 = fmaxf(bc2, o2 ? s4[2] : NEGF);
        sm2 = fmaxf(sm2, o2 ? NEGF : s4[2]);
        bc3 = fmaxf(bc3, o3 ? s4[3] : NEGF);
        sm3 = fmaxf(sm3, o3 ? NEGF : s4[3]);
    }
    // Scalar peel [0,p) and tail [t0,row): <=3 elems each.
    if (lane < p) {
        const float s = arow[lane], m = mrow[lane];
        if (m != 0.0f) bc0 = fmaxf(bc0, s); else sm0 = fmaxf(sm0, s);
    }
    if (lane < row - t0) {
        const int j = t0 + lane;
        const float s = arow[j], m = mrow[j];
        if (m != 0.0f) bc1 = fmaxf(bc1, s); else sm1 = fmaxf(sm1, s);
    }
    bc_out = fmaxf(fmaxf(bc0, bc1), fmaxf(bc2, bc3));
    sm_out = fmaxf(fmaxf(sm0, sm1), fmaxf(sm2, sm3));
}

__device__ __forceinline__ void epilogue(
    const float* __restrict__ eps_scores,
    const float* __restrict__ mask,
    const float* __restrict__ link_costs,
    const float* __restrict__ false_new_cost,
    float* __restrict__ out,
    const int row, float B, float S)
{
    const float e = eps_scores[row];
    const float d = mask[(size_t)row * N + row];   // diag of solution mask
    if (d != 0.0f) B = fmaxf(B, e);                // epsilon is a correct antecedent
    const float rc = d * link_costs[0] + (1.0f - d) * link_costs[1];
    float loss = fmaxf(0.0f, rc * (1.0f + S - B));
    if (d == 0.0f) loss = fmaxf(loss, false_new_cost[0] * (1.0f + e - B));
    out[row] = loss;
}

// One wave per row-pair (4095-w, w): exactly 4095 elements per wave, perfect
// static balance. 512 blocks x 4 waves = 2048 waves -- entire grid co-resident
// (<= 8192 wave capacity), no dispatch rounds, no __syncthreads, no LDS.
__global__ __launch_bounds__(BLK) void mention_loss_kernel(
    const float* __restrict__ eps_scores,
    const float* __restrict__ ana_scores,
    const float* __restrict__ mask,
    const float* __restrict__ link_costs,
    const float* __restrict__ false_new_cost,
    float* __restrict__ out)
{
    const int lane = threadIdx.x & 63;
    const int w    = ((int)blockIdx.x << 2) | (threadIdx.x >> 6);  // 0..2047
    const int rowA = N - 1 - w;   // long row  (2048..4095)
    const int rowB = w;           // short row (0..2047)

    float bcA, smA, bcB, smB;
    scan_row_wave(ana_scores, mask, rowA, lane, bcA, smA);
    scan_row_wave(ana_scores, mask, rowB, lane, bcB, smB);

    // Joint 64-lane butterfly for both rows' (bc, sm).
    for (int off = 32; off; off >>= 1) {
        bcA = fmaxf(bcA, __shfl_down(bcA, off));
        smA = fmaxf(smA, __shfl_down(smA, off));
        bcB = fmaxf(bcB, __shfl_down(bcB, off));
        smB = fmaxf(smB, __shfl_down(smB, off));
    }
    if (lane == 0) {
        epilogue(eps_scores, mask, link_costs, false_new_cost, out, rowA, bcA, smA);
        epilogue(eps_scores, mask, link_costs, false_new_cost, out, rowB, bcB, smB);
    }
}

extern "C" void kernel_launch(void* const* d_in, const int* in_sizes, int n_in,
                              void* d_out, int out_size, void* d_ws, size_t ws_size,
                              hipStream_t stream) {
    const float* eps  = (const float*)d_in[0];
    const float* ana  = (const float*)d_in[1];
    const float* mask = (const float*)d_in[2];
    const float* lc   = (const float*)d_in[3];
    const float* fnc  = (const float*)d_in[4];
    float* out = (float*)d_out;

    mention_loss_kernel<<<N / 8, BLK, 0, stream>>>(eps, ana, mask, lc, fnc, out);
}